// Round 6
// baseline (495.439 us; speedup 1.0000x reference)
//
#include <hip/hip_runtime.h>

// x[8,25,256,256] (fp32) conv w[100,25,9,9] VALID -> out[8,100,248,248] (fp32)
// Implicit GEMM on bf16 MFMA 16x16x32.
// v6: (a) a-frag pipeline deepened to 3 static buffers (2-phase ~390cy cover
// for the ~200-300cy L2-hit weight loads; dbuf's 1-phase ~195cy was marginal),
// made ky-seamless: at kx=7/8 issue next-ky kx=0/1 (KX=9/10 off the same wky
// base; last ky reads p=81/82 -> ws pad, garbage, never consumed).
// (b) T5 s_setprio(1) around each 28-MFMA cluster (phase-diverse co-resident
// blocks = the regime where setprio pays). Swizzle kept (conflicts 2.9e5).
// Staging kept mid-body. launch_bounds (256,2) — (256,4) spills (round 3).

#define NB   8
#define NC   25
#define C32  32
#define NH   256
#define NW   256
#define NOC  100
#define MT   7      // 7 M-tiles of 16 -> 112 (oc padded)
#define KH_  9
#define KW_  9
#define OH   248
#define OW   248

typedef __attribute__((ext_vector_type(8))) short bf16x8;
typedef __attribute__((ext_vector_type(4))) float f32x4;

// ws layout: [wf: 81*7*64*8 bf16][pad to 1 MiB][xt: 8*256*256*32 bf16 = 33.5 MB]
#define WF_ELEMS   (KH_ * KW_ * MT * 64 * 8)          // 290,304
#define WF_BLOCKS  (WF_ELEMS / 256)                   // 1134 exact
#define XT_OFFSET  (1 << 20)

__device__ __forceinline__ unsigned short f2bf(float f) {
    unsigned u = __float_as_uint(f);
    return (unsigned short)((u + 0x7FFFu + ((u >> 16) & 1u)) >> 16);
}

// async global->LDS, 16B per lane; LDS dest = wave-uniform base + lane*16
__device__ __forceinline__ void gll16(const short* g, short* l) {
    __builtin_amdgcn_global_load_lds(
        (const __attribute__((address_space(1))) void*)g,
        (__attribute__((address_space(3))) void*)l, 16, 0, 0);
}

// LDS swizzle on short-offsets: flip 16B-slot bits (3-4) by (col>>1)&3 (bits 6-7).
// Involution; preserves 16B alignment. Same function on stage-src and read.
// Verified on HW (round 3): bank conflicts 1.03e7 -> 2.9e5, absmax unchanged.
__device__ __forceinline__ int swz(int o) { return o ^ ((o >> 3) & 24); }

// ---- merged prep: [0, WF_BLOCKS) -> weights; rest -> xt transpose ----
// wf[(p*7 + mt)*64 + lane][j], p = ky*9+kx; A[m][k]: m = oc = mt*16+(lane&15),
// k = c = (lane>>4)*8 + j
// xt[b][y][x][c32] bf16 from x[b][c][y][x] fp32 via LDS transpose
__global__ __launch_bounds__(256)
void prep(const float* __restrict__ w, const float* __restrict__ x,
          short* __restrict__ wf, short* __restrict__ xt) {
    if (blockIdx.x < WF_BLOCKS) {
        int idx = blockIdx.x * 256 + threadIdx.x;
        if (idx >= WF_ELEMS) return;
        int j    = idx & 7;
        int lane = (idx >> 3) & 63;
        int rest = idx >> 9;
        int mt   = rest % MT;
        int p    = rest / MT;
        int ky   = p / KW_;
        int kx   = p % KW_;
        int oc   = mt * 16 + (lane & 15);
        int c    = (lane >> 4) * 8 + j;
        float v = 0.0f;
        if (oc < NOC && c < NC)
            v = w[(((size_t)oc * NC + c) * KH_ + ky) * KW_ + kx];
        wf[idx] = (short)f2bf(v);
    } else {
        __shared__ short row[NC][NW];          // 12.8 KB
        const int bid = blockIdx.x - WF_BLOCKS;
        const int b = bid >> 8;
        const int y = bid & 255;
        const float* src = x + ((size_t)b * NC) * NH * NW + (size_t)y * NW;

        // coalesced float4 loads: 25 rows x 64 float4
        for (int i = threadIdx.x; i < NC * 64; i += 256) {
            int c  = i >> 6;
            int xq = (i & 63) << 2;
            float4 v = *(const float4*)(src + (size_t)c * NH * NW + xq);
            unsigned short s[4] = { f2bf(v.x), f2bf(v.y), f2bf(v.z), f2bf(v.w) };
            *(unsigned long long*)&row[c][xq] = *(const unsigned long long*)s;
        }
        __syncthreads();

        const int xc = threadIdx.x;
        unsigned short v[C32];
        #pragma unroll
        for (int c = 0; c < NC; ++c) v[c] = (unsigned short)row[c][xc];
        #pragma unroll
        for (int c = NC; c < C32; ++c) v[c] = 0;
        short* dst = xt + (((size_t)b * NH + y) * NW + xc) * C32;
        #pragma unroll
        for (int i = 0; i < 4; ++i)
            ((int4*)dst)[i] = ((const int4*)v)[i];
    }
}

// ---- main: one block = one output row (b, oy); 4 waves x N=64; M=112 ----
// KX may be 9/10 = next ky's kx 0/1 (same wky base); ky=8 reads ws pad (unused).
#define LOADA(A, KX)                                                          \
    { _Pragma("unroll")                                                       \
      for (int mt = 0; mt < MT; ++mt)                                         \
          A[mt] = *(const bf16x8*)(wky + (KX) * 3584 + mt * 512); }

#define LOADB(B, KX)                                                          \
    { _Pragma("unroll")                                                       \
      for (int nt = 0; nt < 4; ++nt) {                                        \
          int col = colb + nt * 16 + (KX);                                    \
          col = col > 255 ? 255 : col;   /* only feeds masked-out cols */     \
          B[nt] = *(const bf16x8*)(lrow + swz(col * C32 + quad * 8)); } }

#define MM(A, B)                                                              \
    { __builtin_amdgcn_s_setprio(1);                                          \
      _Pragma("unroll")                                                       \
      for (int nt = 0; nt < 4; ++nt)                                          \
          _Pragma("unroll")                                                   \
          for (int mt = 0; mt < MT; ++mt)                                     \
              acc[mt][nt] = __builtin_amdgcn_mfma_f32_16x16x32_bf16(          \
                  A[mt], B[nt], acc[mt][nt], 0, 0, 0);                        \
      __builtin_amdgcn_s_setprio(0); }

__global__ __launch_bounds__(256, 2)
void conv_mfma(const short* __restrict__ wf, const short* __restrict__ xt,
               const float* __restrict__ bias, float* __restrict__ out) {
    __shared__ __align__(16) short rowbuf[2][NW * C32];   // 2 x 16 KB

    const int bx   = blockIdx.x;                 // 0..247
    const int oy   = (bx & 7) * 31 + (bx >> 3);  // XCD-aware: contiguous oy per XCD
    const int b    = blockIdx.y;
    const int lane = threadIdx.x & 63;
    const int wv   = threadIdx.x >> 6;
    const int n    = lane & 15;
    const int quad = lane >> 4;
    const int x0w  = wv * 64;
    const int colb = x0w + n;

    // per-lane pre-swizzled global source offset for staging (shorts):
    // dest slot of lane l is (col = chunk*16 + (l>>2), s = l&3); content must be
    // xt[col][s ^ ((col>>1)&3)]; xor reduces to (l>>3)&3 -> swz(lane*8).
    const int ssrc = swz(lane * 8);

    f32x4 acc[MT][4];
    #pragma unroll
    for (int mt = 0; mt < MT; ++mt)
        #pragma unroll
        for (int nt = 0; nt < 4; ++nt)
            acc[mt][nt] = (f32x4){0.f, 0.f, 0.f, 0.f};

    const short* xbase = xt + ((size_t)b * NH + oy) * NW * C32;

    // prologue: stage row oy -> rowbuf[0] (4 chunks of 1 KB per wave)
    #pragma unroll
    for (int i = 0; i < 4; ++i) {
        const int chunk = i * 4 + wv;
        gll16(xbase + chunk * 512 + ssrc, &rowbuf[0][chunk * 512]);
    }

    bf16x8 a0[MT], a1[MT], a2[MT], b0[4], b1[4];
    {   // prime the a-pipeline (p=0,1) before the staging barrier
        const short* wky = wf + lane * 8;
        LOADA(a0, 0);
        LOADA(a1, 1);
    }
    __syncthreads();   // compiler drains vmcnt(0) before s_barrier

    for (int ky = 0; ky < 9; ++ky) {
        const short* lrow = rowbuf[ky & 1];
        const short* wky  = wf + (size_t)ky * 9 * 3584 + lane * 8;

        // a-rotation: MM(kx) uses a[kx%3]; LOADA targets slot (kx+2)%3 (the
        // one consumed at kx-1). b: MM(kx) uses b[kx&1]; load 1 phase ahead.
        LOADB(b0, 0); LOADB(b1, 1);
        LOADA(a2, 2);                MM(a0, b0);   // kx=0
        LOADA(a0, 3); LOADB(b0, 2);  MM(a1, b1);   // kx=1
        LOADA(a1, 4); LOADB(b1, 3);  MM(a2, b0);   // kx=2
        LOADA(a2, 5); LOADB(b0, 4);  MM(a0, b1);   // kx=3
        LOADA(a0, 6); LOADB(b1, 5);  MM(a1, b0);   // kx=4

        // stage next row mid-body: ~4 MM-phases of cover before barrier drain
        if (ky < 8) {
            const short* srcn = xbase + (size_t)(ky + 1) * NW * C32;
            short* ldst = rowbuf[(ky & 1) ^ 1];
            #pragma unroll
            for (int i = 0; i < 4; ++i) {
                const int chunk = i * 4 + wv;
                gll16(srcn + chunk * 512 + ssrc, ldst + chunk * 512);
            }
        }

        LOADA(a1, 7); LOADB(b0, 6);  MM(a2, b1);   // kx=5
        LOADA(a2, 8); LOADB(b1, 7);  MM(a0, b0);   // kx=6
        LOADA(a0, 9); LOADB(b0, 8);  MM(a1, b1);   // kx=7 (a0 <- next ky kx0)
        LOADA(a1, 10);               MM(a2, b0);   // kx=8 (a1 <- next ky kx1)

        if (ky < 8) __syncthreads();
    }

    // epilogue: C/D layout col = lane&15 (ox), row = quad*4 + r (oc)
    #pragma unroll
    for (int mt = 0; mt < MT; ++mt) {
        #pragma unroll
        for (int nt = 0; nt < 4; ++nt) {
            int ox = x0w + nt * 16 + n;
            if (ox >= OW) continue;
            #pragma unroll
            for (int r = 0; r < 4; ++r) {
                int oc = mt * 16 + quad * 4 + r;
                if (oc < NOC)
                    out[(((size_t)b * NOC + oc) * OH + oy) * OW + ox] =
                        acc[mt][nt][r] + bias[oc];
            }
        }
    }
}

extern "C" void kernel_launch(void* const* d_in, const int* in_sizes, int n_in,
                              void* d_out, int out_size, void* d_ws, size_t ws_size,
                              hipStream_t stream) {
    const float* pic  = (const float*)d_in[0];
    const float* wgt  = (const float*)d_in[1];
    const float* bias = (const float*)d_in[2];
    float* out        = (float*)d_out;

    short* wf = (short*)d_ws;
    short* xt = (short*)((char*)d_ws + XT_OFFSET);

    hipLaunchKernelGGL(prep, dim3(WF_BLOCKS + NB * NH), dim3(256), 0, stream,
                       wgt, pic, wf, xt);
    hipLaunchKernelGGL(conv_mfma, dim3(OH, NB), dim3(256), 0, stream, wf, xt, bias, out);
}

// Round 7
// 492.953 us; speedup vs baseline: 1.0050x; 1.0050x over previous
//
#include <hip/hip_runtime.h>

// x[8,25,256,256] (fp32) conv w[100,25,9,9] VALID -> out[8,100,248,248] (fp32)
// Implicit GEMM on bf16 MFMA 16x16x32.
// v7: BARRIER-FREE main loop. Each wave stages its OWN 80-col xt window
// (5x global_load_lds, 5KB) into a private LDS double-buffer -> no
// __syncthreads in the ky loop; per-wave `s_waitcnt vmcnt(0)` at ky top
// (staging issued mid-previous-ky = ~4 phases of cover). Kills the
// correlated all-wave stall that the per-ky barrier manufactured
// (v5: MfmaUtil 46.5 + VALU 23 = 70% busy, 30% dual-idle).
// Seamless a-prime: next-ky kx0/kx1 issued at kx7/kx8 lines into the same
// 2 buffers (ky-parity name alternation, register-neutral — v6's 3rd buffer
// spilled: VGPR 128 + 97MB scratch traffic, 311us REGRESSION; reverted).
// Swizzle kept (verified: conflicts 1.03e7 -> 2.9e5). No setprio (v6 bundled
// it; untested alone). launch_bounds (256,2) — (256,4) spills (round 3).

#define NB   8
#define NC   25
#define C32  32
#define NH   256
#define NW   256
#define NOC  100
#define MT   7      // 7 M-tiles of 16 -> 112 (oc padded)
#define KH_  9
#define KW_  9
#define OH   248
#define OW   248
#define WCOL 80     // per-wave staged window: x0w .. x0w+79 (need <= x0w+71)

typedef __attribute__((ext_vector_type(8))) short bf16x8;
typedef __attribute__((ext_vector_type(4))) float f32x4;

// ws layout: [wf: 81*7*64*8 bf16][pad to 1 MiB][xt: 8*256*256*32 bf16 = 33.5 MB]
#define WF_ELEMS   (KH_ * KW_ * MT * 64 * 8)          // 290,304
#define WF_BLOCKS  (WF_ELEMS / 256)                   // 1134 exact
#define XT_OFFSET  (1 << 20)

__device__ __forceinline__ unsigned short f2bf(float f) {
    unsigned u = __float_as_uint(f);
    return (unsigned short)((u + 0x7FFFu + ((u >> 16) & 1u)) >> 16);
}

// async global->LDS, 16B per lane; LDS dest = wave-uniform base + lane*16
__device__ __forceinline__ void gll16(const short* g, short* l) {
    __builtin_amdgcn_global_load_lds(
        (const __attribute__((address_space(1))) void*)g,
        (__attribute__((address_space(3))) void*)l, 16, 0, 0);
}

// LDS swizzle on short-offsets: flip 16B-slot bits (3-4) by (col>>1)&3.
// Involution; verified on HW (round 3/5): conflicts 1.03e7 -> 2.9e5.
__device__ __forceinline__ int swz(int o) { return o ^ ((o >> 3) & 24); }

// ---- merged prep: [0, WF_BLOCKS) -> weights; rest -> xt transpose ----
__global__ __launch_bounds__(256)
void prep(const float* __restrict__ w, const float* __restrict__ x,
          short* __restrict__ wf, short* __restrict__ xt) {
    if (blockIdx.x < WF_BLOCKS) {
        int idx = blockIdx.x * 256 + threadIdx.x;
        if (idx >= WF_ELEMS) return;
        int j    = idx & 7;
        int lane = (idx >> 3) & 63;
        int rest = idx >> 9;
        int mt   = rest % MT;
        int p    = rest / MT;
        int ky   = p / KW_;
        int kx   = p % KW_;
        int oc   = mt * 16 + (lane & 15);
        int c    = (lane >> 4) * 8 + j;
        float v = 0.0f;
        if (oc < NOC && c < NC)
            v = w[(((size_t)oc * NC + c) * KH_ + ky) * KW_ + kx];
        wf[idx] = (short)f2bf(v);
    } else {
        __shared__ short row[NC][NW];          // 12.8 KB
        const int bid = blockIdx.x - WF_BLOCKS;
        const int b = bid >> 8;
        const int y = bid & 255;
        const float* src = x + ((size_t)b * NC) * NH * NW + (size_t)y * NW;

        for (int i = threadIdx.x; i < NC * 64; i += 256) {
            int c  = i >> 6;
            int xq = (i & 63) << 2;
            float4 v = *(const float4*)(src + (size_t)c * NH * NW + xq);
            unsigned short s[4] = { f2bf(v.x), f2bf(v.y), f2bf(v.z), f2bf(v.w) };
            *(unsigned long long*)&row[c][xq] = *(const unsigned long long*)s;
        }
        __syncthreads();

        const int xc = threadIdx.x;
        unsigned short v[C32];
        #pragma unroll
        for (int c = 0; c < NC; ++c) v[c] = (unsigned short)row[c][xc];
        #pragma unroll
        for (int c = NC; c < C32; ++c) v[c] = 0;
        short* dst = xt + (((size_t)b * NH + y) * NW + xc) * C32;
        #pragma unroll
        for (int i = 0; i < 4; ++i)
            ((int4*)dst)[i] = ((const int4*)v)[i];
    }
}

// ---- main: one block = one output row (b, oy); 4 waves x N=64; M=112 ----
// KX may be 9/10 = next ky's kx 0/1 (same wky base); ky=8 reads ws pad (unused).
#define LOADA(A, KX)                                                          \
    { _Pragma("unroll")                                                       \
      for (int mt = 0; mt < MT; ++mt)                                         \
          A[mt] = *(const bf16x8*)(wky + (KX) * 3584 + mt * 512); }

// window-local col lc = nt*16 + n + KX in [0, 72) < WCOL; no clamp needed
#define LOADB(B, KX)                                                          \
    { _Pragma("unroll")                                                       \
      for (int nt = 0; nt < 4; ++nt) {                                        \
          int lc = nt * 16 + n + (KX);                                        \
          B[nt] = *(const bf16x8*)(lrow + swz(lc * C32 + quad * 8)); } }

#define MM(A, B)                                                              \
    { _Pragma("unroll")                                                       \
      for (int nt = 0; nt < 4; ++nt)                                          \
          _Pragma("unroll")                                                   \
          for (int mt = 0; mt < MT; ++mt)                                     \
              acc[mt][nt] = __builtin_amdgcn_mfma_f32_16x16x32_bf16(          \
                  A[mt], B[nt], acc[mt][nt], 0, 0, 0); }

// per-wave private staging: 5 chunks x 1024B; src col clamped at 255 (clamped
// cols only feed masked-out outputs); source pre-swizzled, LDS dest linear
#define STAGE(XROW, LDST)                                                     \
    { _Pragma("unroll")                                                       \
      for (int ch = 0; ch < 5; ++ch) {                                        \
          int sc = x0w + ch * 16 + lq;                                        \
          sc = sc > 255 ? 255 : sc;                                           \
          gll16((XROW) + (size_t)sc * C32 + slotoff, (LDST) + ch * 512); } }

// one ky iteration; AX = buffer consumed at even kx (0,2,..,8), AY at odd.
// Seamless: kx8 line primes next ky's kx0 into AY (before MM) and kx1 into
// AX (after MM) -> next ky is KYBODY(AY, AX, ...).
#define KYBODY(AX, AY, KY, DOSTAGE)                                           \
  { const short* lrow = mybuf + ((KY) & 1) * (2 * WCOL * C32 / 2);            \
    const short* wky  = wf + (size_t)(KY) * 9 * 3584 + lane * 8;              \
    asm volatile("s_waitcnt vmcnt(0)" ::: "memory");                          \
    LOADB(b0, 0); LOADB(b1, 1);                                               \
    MM(AX, b0);                                   /* kx=0 */                  \
    LOADA(AX, 2); LOADB(b0, 2); MM(AY, b1);       /* kx=1 */                  \
    LOADA(AY, 3); LOADB(b1, 3); MM(AX, b0);       /* kx=2 */                  \
    LOADA(AX, 4); LOADB(b0, 4); MM(AY, b1);       /* kx=3 */                  \
    LOADA(AY, 5); LOADB(b1, 5); MM(AX, b0);       /* kx=4 */                  \
    if (DOSTAGE) STAGE(xbase + (size_t)((KY) + 1) * NW * C32,                 \
                       mybuf + ((((KY) & 1) ^ 1) * (2 * WCOL * C32 / 2)));    \
    LOADA(AX, 6); LOADB(b0, 6); MM(AY, b1);       /* kx=5 */                  \
    LOADA(AY, 7); LOADB(b1, 7); MM(AX, b0);       /* kx=6 */                  \
    LOADA(AX, 8); LOADB(b0, 8); MM(AY, b1);       /* kx=7 */                  \
    LOADA(AY, 9); MM(AX, b0); LOADA(AX, 10);      /* kx=8 + next-ky prime */  \
  }

__global__ __launch_bounds__(256, 2)
void conv_mfma(const short* __restrict__ wf, const short* __restrict__ xt,
               const float* __restrict__ bias, float* __restrict__ out) {
    __shared__ __align__(16) short rowbuf[4][2][WCOL * C32];   // 40 KB

    const int bx   = blockIdx.x;                 // 0..247
    const int oy   = (bx & 7) * 31 + (bx >> 3);  // XCD-aware: contiguous oy per XCD
    const int b    = blockIdx.y;
    const int lane = threadIdx.x & 63;
    const int wv   = threadIdx.x >> 6;
    const int n    = lane & 15;
    const int quad = lane >> 4;
    const int x0w  = wv * 64;

    // staging address pieces (pre-swizzled source; dest linear per gll16)
    const int lq      = lane >> 2;                               // dest col within chunk
    const int slotoff = (((lane & 3) ^ ((lane >> 3) & 3)) * 8);  // swizzled slot

    short* mybuf = &rowbuf[wv][0][0];

    f32x4 acc[MT][4];
    #pragma unroll
    for (int mt = 0; mt < MT; ++mt)
        #pragma unroll
        for (int nt = 0; nt < 4; ++nt)
            acc[mt][nt] = (f32x4){0.f, 0.f, 0.f, 0.f};

    const short* xbase = xt + ((size_t)b * NH + oy) * NW * C32;

    bf16x8 a0[MT], a1[MT], b0[4], b1[4];

    // prologue: stage ky=0 window into buf0; prime a for kx=0/1
    STAGE(xbase, mybuf);
    { const short* wky = wf + lane * 8; LOADA(a0, 0); LOADA(a1, 1); }

    // 9 ky iterations, a-name parity alternates; no barriers anywhere
    for (int k = 0; k < 4; ++k) {
        KYBODY(a0, a1, 2 * k,     1);
        KYBODY(a1, a0, 2 * k + 1, 1);
    }
    KYBODY(a0, a1, 8, 0);

    // epilogue: C/D layout col = lane&15 (ox), row = quad*4 + r (oc)
    #pragma unroll
    for (int mt = 0; mt < MT; ++mt) {
        #pragma unroll
        for (int nt = 0; nt < 4; ++nt) {
            int ox = x0w + nt * 16 + n;
            if (ox >= OW) continue;
            #pragma unroll
            for (int r = 0; r < 4; ++r) {
                int oc = mt * 16 + quad * 4 + r;
                if (oc < NOC)
                    out[(((size_t)b * NOC + oc) * OH + oy) * OW + ox] =
                        acc[mt][nt][r] + bias[oc];
            }
        }
    }
}

extern "C" void kernel_launch(void* const* d_in, const int* in_sizes, int n_in,
                              void* d_out, int out_size, void* d_ws, size_t ws_size,
                              hipStream_t stream) {
    const float* pic  = (const float*)d_in[0];
    const float* wgt  = (const float*)d_in[1];
    const float* bias = (const float*)d_in[2];
    float* out        = (float*)d_out;

    short* wf = (short*)d_ws;
    short* xt = (short*)((char*)d_ws + XT_OFFSET);

    hipLaunchKernelGGL(prep, dim3(WF_BLOCKS + NB * NH), dim3(256), 0, stream,
                       wgt, pic, wf, xt);
    hipLaunchKernelGGL(conv_mfma, dim3(OH, NB), dim3(256), 0, stream, wf, xt, bias, out);
}

// Round 8
// 430.249 us; speedup vs baseline: 1.1515x; 1.1457x over previous
//
#include <hip/hip_runtime.h>

// x[8,25,256,256] (fp32) conv w[100,25,9,9] VALID -> out[8,100,248,248] (fp32)
// Implicit GEMM on bf16 MFMA 16x16x32.
// v8 = v5 (282us plateau: swizzled shared rowbuf, mid-body staging, (256,2))
//      + T5 s_setprio around each 28-MFMA cluster. SINGLE-VARIABLE test:
// theory = 2 waves/SIMD entrain into the same phase (pipe-sharing equalizes
// progress), so both hit their load sections together -> ~30% dual-idle.
// setprio breaks the symmetry (MFMA wave monopolizes, co-wave anti-phases).
// v6 (3rd a-buf, spilled) and v7 (barrier-free, spilled) both proved the
// register wall: 112 AGPR + ~104 VGPR = 216/256; zero-register changes only.

#define NB   8
#define NC   25
#define C32  32
#define NH   256
#define NW   256
#define NOC  100
#define MT   7      // 7 M-tiles of 16 -> 112 (oc padded)
#define KH_  9
#define KW_  9
#define OH   248
#define OW   248

typedef __attribute__((ext_vector_type(8))) short bf16x8;
typedef __attribute__((ext_vector_type(4))) float f32x4;

// ws layout: [wf: 81*7*64*8 bf16][pad to 1 MiB][xt: 8*256*256*32 bf16 = 33.5 MB]
#define WF_ELEMS   (KH_ * KW_ * MT * 64 * 8)          // 290,304
#define WF_BLOCKS  (WF_ELEMS / 256)                   // 1134 exact
#define XT_OFFSET  (1 << 20)

__device__ __forceinline__ unsigned short f2bf(float f) {
    unsigned u = __float_as_uint(f);
    return (unsigned short)((u + 0x7FFFu + ((u >> 16) & 1u)) >> 16);
}

// async global->LDS, 16B per lane; LDS dest = wave-uniform base + lane*16
__device__ __forceinline__ void gll16(const short* g, short* l) {
    __builtin_amdgcn_global_load_lds(
        (const __attribute__((address_space(1))) void*)g,
        (__attribute__((address_space(3))) void*)l, 16, 0, 0);
}

// LDS swizzle on short-offsets: flip 16B-slot bits (3-4) by (col>>1)&3 (bits 6-7).
// Involution; preserves 16B alignment. Same function on stage-src and read.
// Verified on HW (rounds 3/5): bank conflicts 1.03e7 -> 2.9e5, absmax unchanged.
__device__ __forceinline__ int swz(int o) { return o ^ ((o >> 3) & 24); }

// ---- merged prep: [0, WF_BLOCKS) -> weights; rest -> xt transpose ----
// wf[(p*7 + mt)*64 + lane][j], p = ky*9+kx; A[m][k]: m = oc = mt*16+(lane&15),
// k = c = (lane>>4)*8 + j
// xt[b][y][x][c32] bf16 from x[b][c][y][x] fp32 via LDS transpose
__global__ __launch_bounds__(256)
void prep(const float* __restrict__ w, const float* __restrict__ x,
          short* __restrict__ wf, short* __restrict__ xt) {
    if (blockIdx.x < WF_BLOCKS) {
        int idx = blockIdx.x * 256 + threadIdx.x;
        if (idx >= WF_ELEMS) return;
        int j    = idx & 7;
        int lane = (idx >> 3) & 63;
        int rest = idx >> 9;
        int mt   = rest % MT;
        int p    = rest / MT;
        int ky   = p / KW_;
        int kx   = p % KW_;
        int oc   = mt * 16 + (lane & 15);
        int c    = (lane >> 4) * 8 + j;
        float v = 0.0f;
        if (oc < NOC && c < NC)
            v = w[(((size_t)oc * NC + c) * KH_ + ky) * KW_ + kx];
        wf[idx] = (short)f2bf(v);
    } else {
        __shared__ short row[NC][NW];          // 12.8 KB
        const int bid = blockIdx.x - WF_BLOCKS;
        const int b = bid >> 8;
        const int y = bid & 255;
        const float* src = x + ((size_t)b * NC) * NH * NW + (size_t)y * NW;

        // coalesced float4 loads: 25 rows x 64 float4
        for (int i = threadIdx.x; i < NC * 64; i += 256) {
            int c  = i >> 6;
            int xq = (i & 63) << 2;
            float4 v = *(const float4*)(src + (size_t)c * NH * NW + xq);
            unsigned short s[4] = { f2bf(v.x), f2bf(v.y), f2bf(v.z), f2bf(v.w) };
            *(unsigned long long*)&row[c][xq] = *(const unsigned long long*)s;
        }
        __syncthreads();

        const int xc = threadIdx.x;
        unsigned short v[C32];
        #pragma unroll
        for (int c = 0; c < NC; ++c) v[c] = (unsigned short)row[c][xc];
        #pragma unroll
        for (int c = NC; c < C32; ++c) v[c] = 0;
        short* dst = xt + (((size_t)b * NH + y) * NW + xc) * C32;
        #pragma unroll
        for (int i = 0; i < 4; ++i)
            ((int4*)dst)[i] = ((const int4*)v)[i];
    }
}

// ---- main: one block = one output row (b, oy); 4 waves x N=64; M=112 ----
#define LOADA(A, KX)                                                          \
    { _Pragma("unroll")                                                       \
      for (int mt = 0; mt < MT; ++mt)                                         \
          A[mt] = *(const bf16x8*)(wky + (KX) * 3584 + mt * 512); }

#define LOADB(B, KX)                                                          \
    { _Pragma("unroll")                                                       \
      for (int nt = 0; nt < 4; ++nt) {                                        \
          int col = colb + nt * 16 + (KX);                                    \
          col = col > 255 ? 255 : col;   /* only feeds masked-out cols */     \
          B[nt] = *(const bf16x8*)(lrow + swz(col * C32 + quad * 8)); } }

#define MM(A, B)                                                              \
    { __builtin_amdgcn_s_setprio(1);                                          \
      _Pragma("unroll")                                                       \
      for (int nt = 0; nt < 4; ++nt)                                          \
          _Pragma("unroll")                                                   \
          for (int mt = 0; mt < MT; ++mt)                                     \
              acc[mt][nt] = __builtin_amdgcn_mfma_f32_16x16x32_bf16(          \
                  A[mt], B[nt], acc[mt][nt], 0, 0, 0);                        \
      __builtin_amdgcn_s_setprio(0); }

__global__ __launch_bounds__(256, 2)
void conv_mfma(const short* __restrict__ wf, const short* __restrict__ xt,
               const float* __restrict__ bias, float* __restrict__ out) {
    __shared__ __align__(16) short rowbuf[2][NW * C32];   // 2 x 16 KB

    const int bx   = blockIdx.x;                 // 0..247
    const int oy   = (bx & 7) * 31 + (bx >> 3);  // XCD-aware: contiguous oy per XCD
    const int b    = blockIdx.y;
    const int lane = threadIdx.x & 63;
    const int wv   = threadIdx.x >> 6;
    const int n    = lane & 15;
    const int quad = lane >> 4;
    const int x0w  = wv * 64;
    const int colb = x0w + n;

    // per-lane pre-swizzled global source offset for staging (shorts):
    // dest slot of lane l is (col = chunk*16 + (l>>2), s = l&3); content must be
    // xt[col][s ^ ((col>>1)&3)]; xor reduces to (l>>3)&3 -> swz(lane*8).
    const int ssrc = swz(lane * 8);

    f32x4 acc[MT][4];
    #pragma unroll
    for (int mt = 0; mt < MT; ++mt)
        #pragma unroll
        for (int nt = 0; nt < 4; ++nt)
            acc[mt][nt] = (f32x4){0.f, 0.f, 0.f, 0.f};

    const short* xbase = xt + ((size_t)b * NH + oy) * NW * C32;

    // prologue: stage row oy -> rowbuf[0] (4 chunks of 1 KB per wave)
    #pragma unroll
    for (int i = 0; i < 4; ++i) {
        const int chunk = i * 4 + wv;
        gll16(xbase + chunk * 512 + ssrc, &rowbuf[0][chunk * 512]);
    }
    __syncthreads();   // compiler drains vmcnt(0) before s_barrier

    for (int ky = 0; ky < 9; ++ky) {
        const short* lrow = rowbuf[ky & 1];
        const short* wky  = wf + (size_t)ky * 9 * 3584 + lane * 8;

        bf16x8 a0[MT], a1[MT], b0[4], b1[4];
        LOADA(a0, 0); LOADB(b0, 0);
        LOADA(a1, 1); LOADB(b1, 1); MM(a0, b0);   // kx=0
        LOADA(a0, 2); LOADB(b0, 2); MM(a1, b1);   // kx=1
        LOADA(a1, 3); LOADB(b1, 3); MM(a0, b0);   // kx=2
        LOADA(a0, 4); LOADB(b0, 4); MM(a1, b1);   // kx=3
        LOADA(a1, 5); LOADB(b1, 5); MM(a0, b0);   // kx=4

        // stage next row mid-body: ~4 MM-phases (~2100 cy) of cover before
        // the barrier drain; younger than no pending a-frag consume.
        if (ky < 8) {
            const short* srcn = xbase + (size_t)(ky + 1) * NW * C32;
            short* ldst = rowbuf[(ky & 1) ^ 1];
            #pragma unroll
            for (int i = 0; i < 4; ++i) {
                const int chunk = i * 4 + wv;
                gll16(srcn + chunk * 512 + ssrc, ldst + chunk * 512);
            }
        }

        LOADA(a0, 6); LOADB(b0, 6); MM(a1, b1);   // kx=5
        LOADA(a1, 7); LOADB(b1, 7); MM(a0, b0);   // kx=6
        LOADA(a0, 8); LOADB(b0, 8); MM(a1, b1);   // kx=7
        MM(a0, b0);                               // kx=8

        if (ky < 8) __syncthreads();
    }

    // epilogue: C/D layout col = lane&15 (ox), row = quad*4 + r (oc)
    #pragma unroll
    for (int mt = 0; mt < MT; ++mt) {
        #pragma unroll
        for (int nt = 0; nt < 4; ++nt) {
            int ox = x0w + nt * 16 + n;
            if (ox >= OW) continue;
            #pragma unroll
            for (int r = 0; r < 4; ++r) {
                int oc = mt * 16 + quad * 4 + r;
                if (oc < NOC)
                    out[(((size_t)b * NOC + oc) * OH + oy) * OW + ox] =
                        acc[mt][nt][r] + bias[oc];
            }
        }
    }
}

extern "C" void kernel_launch(void* const* d_in, const int* in_sizes, int n_in,
                              void* d_out, int out_size, void* d_ws, size_t ws_size,
                              hipStream_t stream) {
    const float* pic  = (const float*)d_in[0];
    const float* wgt  = (const float*)d_in[1];
    const float* bias = (const float*)d_in[2];
    float* out        = (float*)d_out;

    short* wf = (short*)d_ws;
    short* xt = (short*)((char*)d_ws + XT_OFFSET);

    hipLaunchKernelGGL(prep, dim3(WF_BLOCKS + NB * NH), dim3(256), 0, stream,
                       wgt, pic, wf, xt);
    hipLaunchKernelGGL(conv_mfma, dim3(OH, NB), dim3(256), 0, stream, wf, xt, bias, out);
}